// Round 13
// baseline (104.344 us; speedup 1.0000x reference)
//
#include <hip/hip_runtime.h>

typedef __attribute__((ext_vector_type(8))) short bf16x8;
typedef __attribute__((ext_vector_type(4))) float f32x4;

// ---------------- workspace layout (float offsets) ----------------
#define WS_CTXPROJ  0         // 64*512
#define WS_SPANPART 32768     // 64*8*2 (+pad)
#define WS_PART     33792     // 4096*16 score partials
#define WS_FEATS    99328     // 2*64*1024
#define WS_PBUF     295936    // 8*64*1024 ctx partials
#define WS_PBUFA    820224    // 16*64*1024 fu partials
#define WS_PBUFB    1868800   // 16*64*1024 gate partials
#define WS_APACK    2917376   // 4096*1024 bf16 (hi only) = 2097152 float-slots
#define WS_BPACK    5014528   // 1024*512 bf16 (hi only) = 262144 float-slots

__device__ __forceinline__ float gelu_f(float x) {
    return 0.5f * x * (1.0f + erff(x * 0.70710678118654752f));
}
__device__ __forceinline__ float sigm_f(float x) {
    return 1.0f / (1.0f + expf(-x));
}
__device__ __forceinline__ short f2bf(float f) {   // RNE float->bf16
    unsigned u = __float_as_uint(f);
    u += 0x7fffu + ((u >> 16) & 1u);
    return (short)(u >> 16);
}

// row r in [0,4096) = p*2048 + pos*64 + b  ->  source seq index s
__device__ __forceinline__ int row_to_s(int r) {
    int p = r >> 11, pos = (r & 2047) >> 6;
    return p ? pos * 128 : 4064 + pos;
}

// ---------------- K1: prep (ctx partials | A-pack | B-pack | attn fill) ----------------
__global__ __launch_bounds__(256) void prep_k(const float* __restrict__ long_x,
                                              const float* __restrict__ enc,
                                              const float* __restrict__ rs_w1,
                                              float* __restrict__ pbuf,
                                              short* __restrict__ Apack,
                                              short* __restrict__ Bpack,
                                              float* __restrict__ attn_out) {
    int blk = blockIdx.x, t = threadIdx.x;
    if (blk < 512) {
        // encoded_x (512,64,1024) -> partial[8][64][1024]
        int gt = blk * 256 + t;
        int chunk = gt >> 14, idx = gt & 16383;   // idx = b*256 + e4
        const float4* src = reinterpret_cast<const float4*>(enc) + idx;
        float sx = 0.f, sy = 0.f, sz = 0.f, sw = 0.f;
        int s0 = chunk * 64;
        for (int s = s0; s < s0 + 64; ++s) {
            float4 v = src[(size_t)s * 16384];
            sx += v.x; sy += v.y; sz += v.z; sw += v.w;
        }
        float4 o; o.x = sx; o.y = sy; o.z = sz; o.w = sw;
        reinterpret_cast<float4*>(pbuf)[(size_t)chunk * 16384 + idx] = o;
    } else if (blk < 1024) {
        // A-pack (hi only), coalesced reads: thread = (row r, kt). 128B contiguous read.
        int ti = (blk - 512) * 256 + t;         // [0, 131072)
        int r  = ti >> 5, kt = ti & 31;
        int b  = r & 63;
        int s  = row_to_s(r);
        const float4* src = reinterpret_cast<const float4*>(
            long_x + ((size_t)s * 64 + b) * 1024 + kt * 32);
        float fs[32];
        #pragma unroll
        for (int q = 0; q < 8; ++q) {
            float4 v = src[q];
            fs[q * 4 + 0] = v.x; fs[q * 4 + 1] = v.y;
            fs[q * 4 + 2] = v.z; fs[q * 4 + 3] = v.w;
        }
        int mt = r >> 4, lo16 = r & 15;
        bf16x8* dst = reinterpret_cast<bf16x8*>(Apack);
        #pragma unroll
        for (int hi4 = 0; hi4 < 4; ++hi4) {
            bf16x8 h;
            #pragma unroll
            for (int j = 0; j < 8; ++j) h[j] = f2bf(fs[hi4 * 8 + j]);
            dst[(size_t)(mt * 32 + kt) * 64 + hi4 * 16 + lo16] = h;
        }
    } else if (blk < 1280) {
        // B-pack (hi only): fragment (nt,kt,lane): rs_w1[kt*32+(l>>4)*8 + j][nt*16+(l&15)]
        int ti = (blk - 1024) * 256 + t;        // [0, 65536)
        int lane = ti & 63, kt = (ti >> 6) & 31, nt = ti >> 11;
        int k0 = kt * 32 + (lane >> 4) * 8;
        int col = nt * 16 + (lane & 15);
        bf16x8 h;
        #pragma unroll
        for (int j = 0; j < 8; ++j) h[j] = f2bf(rs_w1[(size_t)(k0 + j) * 512 + col]);
        reinterpret_cast<bf16x8*>(Bpack)[ti] = h;
    } else {
        // attn = 1/4096 : 65536 float4
        int i = (blk - 1280) * 256 + t;
        float4 v; v.x = v.y = v.z = v.w = (1.0f / 4096.0f);
        reinterpret_cast<float4*>(attn_out)[i] = v;
    }
}

// ---------------- K2: heads v4 — 512 thr (8 K-strips), 2 waves/SIMD ----------------
__global__ __launch_bounds__(512) void heads_k(const float* __restrict__ pbuf,
                                               const float* __restrict__ rs_w1,
                                               const float* __restrict__ rs_b1,
                                               const float* __restrict__ sp_w1,
                                               const float* __restrict__ sp_b1,
                                               const float* __restrict__ sp_w2,
                                               const float* __restrict__ sp_b2,
                                               float* __restrict__ ctxproj,
                                               float* __restrict__ spanpart) {
    __shared__ float c4[4][1024];
    __shared__ float sums[8][64][4];
    __shared__ float r0[4][64], r1[4][64];
    int blk = blockIdx.x, t = threadIdx.x;
    int role = blk >> 7;
    int bq = (blk >> 3) & 15, jc = blk & 7;
    int b0 = bq * 4, j0 = jc * 64;
    for (int e = t; e < 4096; e += 512) {
        int b = e >> 10, k = e & 1023;
        float s = 0.f;
        #pragma unroll
        for (int cc = 0; cc < 8; ++cc) s += pbuf[((size_t)(cc * 64 + b0 + b)) * 1024 + k];
        c4[b][k] = s * (1.0f / 512.0f);
    }
    __syncthreads();
    int jl = t & 63, kh = t >> 6;     // kh 0..7, strips of 128 k
    int j = j0 + jl;
    const float* w = (role == 0 ? rs_w1 + (size_t)1024 * 512 : sp_w1)
                     + (size_t)(kh * 128) * 512 + j;
    float acc[4] = {0.f, 0.f, 0.f, 0.f};
    #pragma unroll 8
    for (int k = 0; k < 128; ++k) {
        float wv = w[(size_t)k * 512];
        int kk = kh * 128 + k;
        acc[0] += c4[0][kk] * wv;
        acc[1] += c4[1][kk] * wv;
        acc[2] += c4[2][kk] * wv;
        acc[3] += c4[3][kk] * wv;
    }
    #pragma unroll
    for (int b = 0; b < 4; ++b) sums[kh][jl][b] = acc[b];
    __syncthreads();
    if (t < 256) {
        int jl2 = t >> 2, b = t & 3;
        float val = 0.f;
        #pragma unroll
        for (int q = 0; q < 8; ++q) val += sums[q][jl2][b];
        int jj = j0 + jl2, gb = b0 + b;
        if (role == 0) {
            ctxproj[(size_t)gb * 512 + jj] = rs_b1[jj] + val;
        } else {
            float h = gelu_f(sp_b1[jj] + val);
            r0[b][jl2] = h * sp_w2[jj * 2 + 0];
            r1[b][jl2] = h * sp_w2[jj * 2 + 1];
        }
    }
    if (role == 1) {
        __syncthreads();
        for (int s = 32; s > 0; s >>= 1) {
            if (t < 4 * s) {
                int bb = t / s, qq = t % s;
                r0[bb][qq] += r0[bb][qq + s];
                r1[bb][qq] += r1[bb][qq + s];
            }
            __syncthreads();
        }
        if (t < 4) {
            spanpart[((size_t)(b0 + t) * 8 + jc) * 2 + 0] = r0[t][0];
            spanpart[((size_t)(b0 + t) * 8 + jc) * 2 + 1] = r1[t][0];
        }
    }
}

// ---------------- K3: score GEMM via MFMA, pure bf16-hi, 8 waves (2 waves/SIMD) -------
__global__ __launch_bounds__(512) void score_mfma_k(const short* __restrict__ Apack_,
                                                    const short* __restrict__ Bpack_,
                                                    const float* __restrict__ ctxproj,
                                                    const float* __restrict__ rs_w2,
                                                    float* __restrict__ part) {
    const bf16x8* Apack = reinterpret_cast<const bf16x8*>(Apack_);
    const bf16x8* Bpack = reinterpret_cast<const bf16x8*>(Bpack_);
    int t = threadIdx.x, lane = t & 63, w = t >> 6;
    int wr = w & 1, wc = w >> 1;                      // 2 x 4 wave grid
    int bm = blockIdx.x & 63, bn = blockIdx.x >> 6;   // XCD-local A-reuse swizzle
    int mt0 = bm * 4 + wr * 2;      // 2 m-fragments
    int nt0 = bn * 8 + wc * 2;      // 2 n-fragments
    f32x4 acc[2][2];
    #pragma unroll
    for (int r = 0; r < 2; ++r)
        #pragma unroll
        for (int i = 0; i < 2; ++i) acc[r][i] = (f32x4){0.f, 0.f, 0.f, 0.f};
    const bf16x8* A0 = Apack + ((size_t)(mt0 + 0) * 2048 + lane);
    const bf16x8* A1 = Apack + ((size_t)(mt0 + 1) * 2048 + lane);
    const bf16x8* B0 = Bpack + ((size_t)(nt0 + 0) * 2048 + lane);
    const bf16x8* B1 = Bpack + ((size_t)(nt0 + 1) * 2048 + lane);
    #pragma unroll 4
    for (int kt = 0; kt < 32; ++kt) {
        bf16x8 a0 = A0[kt * 64];
        bf16x8 a1 = A1[kt * 64];
        bf16x8 b0 = B0[kt * 64];
        bf16x8 b1 = B1[kt * 64];
        acc[0][0] = __builtin_amdgcn_mfma_f32_16x16x32_bf16(a0, b0, acc[0][0], 0, 0, 0);
        acc[0][1] = __builtin_amdgcn_mfma_f32_16x16x32_bf16(a0, b1, acc[0][1], 0, 0, 0);
        acc[1][0] = __builtin_amdgcn_mfma_f32_16x16x32_bf16(a1, b0, acc[1][0], 0, 0, 0);
        acc[1][1] = __builtin_amdgcn_mfma_f32_16x16x32_bf16(a1, b1, acc[1][1], 0, 0, 0);
    }
    int hi = lane >> 4, lo = lane & 15;
    int c0 = (nt0 + 0) * 16 + lo, c1 = (nt0 + 1) * 16 + lo;
    float w2c0 = rs_w2[c0], w2c1 = rs_w2[c1];
    float pl[8];
    #pragma unroll
    for (int rr = 0; rr < 2; ++rr) {
        #pragma unroll
        for (int reg = 0; reg < 4; ++reg) {
            int row = (mt0 + rr) * 16 + hi * 4 + reg;
            int b = row & 63;
            pl[rr * 4 + reg] =
                gelu_f(acc[rr][0][reg] + ctxproj[(size_t)b * 512 + c0]) * w2c0 +
                gelu_f(acc[rr][1][reg] + ctxproj[(size_t)b * 512 + c1]) * w2c1;
        }
    }
    #pragma unroll
    for (int m = 1; m < 16; m <<= 1) {
        #pragma unroll
        for (int q = 0; q < 8; ++q) pl[q] += __shfl_xor(pl[q], m, 64);
    }
    if (lo == 0) {
        int chunk = bn * 4 + wc;   // [0,16)
        #pragma unroll
        for (int rr = 0; rr < 2; ++rr)
            #pragma unroll
            for (int reg = 0; reg < 4; ++reg) {
                int row = (mt0 + rr) * 16 + hi * 4 + reg;
                part[(size_t)row * 16 + chunk] = pl[rr * 4 + reg];
            }
    }
}

// ---------------- K4: pool v3 — 256 blocks x 256 thr (block = p,b,e4-half) ------------
__global__ __launch_bounds__(256) void pool_k(const float* __restrict__ long_x,
                                              const float* __restrict__ part,
                                              const float* __restrict__ rs_b2,
                                              const float* __restrict__ decay_l,
                                              const float* __restrict__ decay_g,
                                              float* __restrict__ feats) {
    __shared__ float red[32][16];
    __shared__ float wl[32];
    __shared__ float4 tmp[128];
    int blk = blockIdx.x;
    int p = blk >> 7, b = (blk >> 1) & 63, hf = blk & 1;
    int t = threadIdx.x;
    for (int i = t; i < 512; i += 256) {
        int pos = i >> 4, cc = i & 15;
        red[pos][cc] = part[(size_t)(p * 2048 + pos * 64 + b) * 16 + cc];
    }
    __syncthreads();
    if (t < 32) {
        float z = rs_b2[0];
        #pragma unroll
        for (int q = 0; q < 16; ++q) z += red[t][q];
        float sc = sigm_f(z);
        float decay = p ? decay_g[0] : decay_l[0];
        float dec = powf(decay, (float)(31 - t));
        wl[t] = sc + logf(dec + 1e-8f);
    }
    __syncthreads();
    if (t == 0) {
        float m = -1e30f;
        for (int j = 0; j < 32; ++j) m = fmaxf(m, wl[j]);
        float ssum = 0.f;
        float e[32];
        for (int j = 0; j < 32; ++j) { e[j] = expf(wl[j] - m); ssum += e[j]; }
        float inv = 1.0f / ssum;
        for (int j = 0; j < 32; ++j) wl[j] = e[j] * inv;
    }
    __syncthreads();
    int e4 = hf * 128 + (t & 127), lh = t >> 7;   // lh 0..1: 16 l each
    float sx = 0.f, sy = 0.f, sz = 0.f, sw = 0.f;
    #pragma unroll 8
    for (int li = 0; li < 16; ++li) {
        int l = lh * 16 + li;
        int s = p ? (l * 128) : (4064 + l);
        float4 v = reinterpret_cast<const float4*>(long_x)[((size_t)s * 64 + b) * 256 + e4];
        float wv = wl[l];
        sx += wv * v.x; sy += wv * v.y; sz += wv * v.z; sw += wv * v.w;
    }
    if (lh == 1) {
        float4 u; u.x = sx; u.y = sy; u.z = sz; u.w = sw;
        tmp[t & 127] = u;
    }
    __syncthreads();
    if (lh == 0) {
        float4 u = tmp[t & 127];
        float4 o; o.x = sx + u.x; o.y = sy + u.y; o.z = sz + u.z; o.w = sw + u.w;
        reinterpret_cast<float4*>(feats)[((size_t)(p * 64 + b)) * 256 + e4] = o;
    }
}

// ---------------- K5: fused partial GEMM (combined @ fu_w), 16-way split-K ------------
__global__ __launch_bounds__(256) void fu_partial_k(const float* __restrict__ feats,
                                                    const float* __restrict__ spanpart,
                                                    const float* __restrict__ sp_b2,
                                                    const float* __restrict__ fu_w,
                                                    float* __restrict__ pbufA) {
    __shared__ float a[64][132];
    __shared__ float sw[64][2];
    int kchunk = blockIdx.x >> 4;   // 0..15 (128 k each)
    int nt     = blockIdx.x & 15;   // 0..15 (64 cols each)
    int t = threadIdx.x;
    if (t < 64) {
        float s0 = 0.f, s1 = 0.f;
        #pragma unroll
        for (int q = 0; q < 8; ++q) {
            s0 += spanpart[((size_t)t * 8 + q) * 2 + 0];
            s1 += spanpart[((size_t)t * 8 + q) * 2 + 1];
        }
        float l0 = s0 + sp_b2[0], l1 = s1 + sp_b2[1];
        float m = fmaxf(l0, l1);
        float e0 = expf(l0 - m), e1 = expf(l1 - m), inv = 1.0f / (e0 + e1);
        sw[t][0] = e0 * inv; sw[t][1] = e1 * inv;
    }
    __syncthreads();
    int p = kchunk >> 3, kbase = (kchunk & 7) * 128;
    int colq = t & 15, bg = t >> 4;
    #pragma unroll
    for (int it = 0; it < 8; ++it) {
        int idx = t + it * 256;            // 2048 float4 = 64 b x 32 kq
        int b = idx >> 5, kq = idx & 31;
        float4 v = *reinterpret_cast<const float4*>(
            feats + ((size_t)(p * 64 + b)) * 1024 + kbase + kq * 4);
        float sc = sw[b][p];
        v.x *= sc; v.y *= sc; v.z *= sc; v.w *= sc;
        *reinterpret_cast<float4*>(&a[b][kq * 4]) = v;
    }
    __syncthreads();
    float acc[4][4] = {};
    #pragma unroll 4
    for (int k = 0; k < 128; ++k) {
        float4 wv = *reinterpret_cast<const float4*>(
            fu_w + (size_t)(kchunk * 128 + k) * 1024 + nt * 64 + colq * 4);
        #pragma unroll
        for (int i = 0; i < 4; ++i) {
            float av = a[bg * 4 + i][k];
            acc[i][0] += av * wv.x; acc[i][1] += av * wv.y;
            acc[i][2] += av * wv.z; acc[i][3] += av * wv.w;
        }
    }
    #pragma unroll
    for (int i = 0; i < 4; ++i) {
        float4 o; o.x = acc[i][0]; o.y = acc[i][1]; o.z = acc[i][2]; o.w = acc[i][3];
        *reinterpret_cast<float4*>(
            pbufA + ((size_t)(kchunk * 64 + bg * 4 + i)) * 1024 + nt * 64 + colq * 4) = o;
    }
}

// ---------------- K6: gate partial GEMM — rebuilds fused inline (parallel, padded) ----
// fused[b][k0..k0+63] = gelu(sum_c pbufA[c][b][...] + fu_b); same sum order as old
// fu_final -> bitwise-identical values. 256 thr stage 1024 float4 cooperatively.
__global__ __launch_bounds__(256) void g_partial_k(const float* __restrict__ pbufA,
                                                   const float* __restrict__ fu_b,
                                                   const float* __restrict__ g_w,
                                                   float* __restrict__ pbufB) {
    __shared__ float a[64][68];
    int kchunk = blockIdx.x >> 4;   // 0..15 (64 k each)
    int nt     = blockIdx.x & 15;
    int t = threadIdx.x;
    int k0 = kchunk * 64;
    #pragma unroll
    for (int it = 0; it < 4; ++it) {
        int idx = t + it * 256;            // 1024 float4 = 64 b x 16 kq
        int b = idx >> 4, kq = idx & 15;
        int kk = k0 + kq * 4;
        float4 z; z.x = fu_b[kk]; z.y = fu_b[kk + 1]; z.z = fu_b[kk + 2]; z.w = fu_b[kk + 3];
        #pragma unroll
        for (int c = 0; c < 16; ++c) {
            float4 v = *reinterpret_cast<const float4*>(
                pbufA + (size_t)c * 65536 + (size_t)b * 1024 + kk);
            z.x += v.x; z.y += v.y; z.z += v.z; z.w += v.w;
        }
        z.x = gelu_f(z.x); z.y = gelu_f(z.y); z.z = gelu_f(z.z); z.w = gelu_f(z.w);
        *reinterpret_cast<float4*>(&a[b][kq * 4]) = z;
    }
    __syncthreads();
    int colq = t & 15, bg = t >> 4;
    float acc[4][4] = {};
    #pragma unroll 4
    for (int k = 0; k < 64; ++k) {
        float4 wv = *reinterpret_cast<const float4*>(
            g_w + (size_t)(k0 + k) * 1024 + nt * 64 + colq * 4);
        #pragma unroll
        for (int i = 0; i < 4; ++i) {
            float av = a[bg * 4 + i][k];
            acc[i][0] += av * wv.x; acc[i][1] += av * wv.y;
            acc[i][2] += av * wv.z; acc[i][3] += av * wv.w;
        }
    }
    #pragma unroll
    for (int i = 0; i < 4; ++i) {
        float4 o; o.x = acc[i][0]; o.y = acc[i][1]; o.z = acc[i][2]; o.w = acc[i][3];
        *reinterpret_cast<float4*>(
            pbufB + ((size_t)(kchunk * 64 + bg * 4 + i)) * 1024 + nt * 64 + colq * 4) = o;
    }
}

// ---------------- K7: adaptive — rebuilds fused inline, gate sum, sigmoid, multiply ---
__global__ __launch_bounds__(256) void g_final_k(const float* __restrict__ pbufA,
                                                 const float* __restrict__ pbufB,
                                                 const float* __restrict__ fu_b,
                                                 const float* __restrict__ g_b,
                                                 float* __restrict__ out_adaptive) {
    int i4 = blockIdx.x * 256 + threadIdx.x;   // 16384 float4
    int bi = (i4 * 4) & 1023;
    // rebuild fused (same order as old fu_final -> bitwise identical)
    float4 f; f.x = fu_b[bi]; f.y = fu_b[bi + 1]; f.z = fu_b[bi + 2]; f.w = fu_b[bi + 3];
    #pragma unroll
    for (int c = 0; c < 16; ++c) {
        float4 v = reinterpret_cast<const float4*>(pbufA)[(size_t)c * 16384 + i4];
        f.x += v.x; f.y += v.y; f.z += v.z; f.w += v.w;
    }
    f.x = gelu_f(f.x); f.y = gelu_f(f.y); f.z = gelu_f(f.z); f.w = gelu_f(f.w);
    // gate sum
    float4 z; z.x = g_b[bi]; z.y = g_b[bi + 1]; z.z = g_b[bi + 2]; z.w = g_b[bi + 3];
    #pragma unroll
    for (int c = 0; c < 16; ++c) {
        float4 v = reinterpret_cast<const float4*>(pbufB)[(size_t)c * 16384 + i4];
        z.x += v.x; z.y += v.y; z.z += v.z; z.w += v.w;
    }
    float4 o;
    o.x = f.x * sigm_f(z.x); o.y = f.y * sigm_f(z.y);
    o.z = f.z * sigm_f(z.z); o.w = f.w * sigm_f(z.w);
    reinterpret_cast<float4*>(out_adaptive)[i4] = o;
}

// ---------------- launch ----------------
extern "C" void kernel_launch(void* const* d_in, const int* in_sizes, int n_in,
                              void* d_out, int out_size, void* d_ws, size_t ws_size,
                              hipStream_t stream) {
    const float* long_x  = (const float*)d_in[0];
    const float* enc     = (const float*)d_in[1];
    const float* sp_w1   = (const float*)d_in[2];
    const float* sp_b1   = (const float*)d_in[3];
    const float* sp_w2   = (const float*)d_in[4];
    const float* sp_b2   = (const float*)d_in[5];
    const float* rs_w1   = (const float*)d_in[6];
    const float* rs_b1   = (const float*)d_in[7];
    const float* rs_w2   = (const float*)d_in[8];
    const float* rs_b2   = (const float*)d_in[9];
    const float* fu_w    = (const float*)d_in[10];
    const float* fu_b    = (const float*)d_in[11];
    const float* g_w     = (const float*)d_in[12];
    const float* g_b     = (const float*)d_in[13];
    const float* decay_l = (const float*)d_in[14];
    const float* decay_g = (const float*)d_in[15];

    float* out = (float*)d_out;
    float* ws  = (float*)d_ws;

    prep_k<<<1536, 256, 0, stream>>>(long_x, enc, rs_w1, ws + WS_PBUF,
                                     (short*)(ws + WS_APACK), (short*)(ws + WS_BPACK), out);
    heads_k<<<256, 512, 0, stream>>>(ws + WS_PBUF, rs_w1, rs_b1, sp_w1, sp_b1, sp_w2, sp_b2,
                                     ws + WS_CTXPROJ, ws + WS_SPANPART);
    score_mfma_k<<<256, 512, 0, stream>>>((short*)(ws + WS_APACK), (short*)(ws + WS_BPACK),
                                          ws + WS_CTXPROJ, rs_w2, ws + WS_PART);
    pool_k<<<256, 256, 0, stream>>>(long_x, ws + WS_PART, rs_b2, decay_l, decay_g,
                                    ws + WS_FEATS);
    fu_partial_k<<<256, 256, 0, stream>>>(ws + WS_FEATS, ws + WS_SPANPART, sp_b2, fu_w,
                                          ws + WS_PBUFA);
    g_partial_k<<<256, 256, 0, stream>>>(ws + WS_PBUFA, fu_b, g_w, ws + WS_PBUFB);
    g_final_k<<<64, 256, 0, stream>>>(ws + WS_PBUFA, ws + WS_PBUFB, fu_b, g_b,
                                      out + 262144);
}

// Round 14
// 98.784 us; speedup vs baseline: 1.0563x; 1.0563x over previous
//
#include <hip/hip_runtime.h>

typedef __attribute__((ext_vector_type(8))) short bf16x8;
typedef __attribute__((ext_vector_type(4))) float f32x4;

// ---------------- workspace layout (float offsets) ----------------
#define WS_CTXPROJ  0         // 64*512
#define WS_SPANPART 32768     // 64*8*2 (+pad)
#define WS_PART     33792     // 4096*16 score partials
#define WS_FEATS    99328     // 2*64*1024
#define WS_FUSED    230400    // 64*1024
#define WS_PBUF     295936    // 8*64*1024 ctx partials
#define WS_PBUFA    820224    // 16*64*1024 fu partials
#define WS_PBUFB    1868800   // 16*64*1024 gate partials
#define WS_APACK    2917376   // 4096*1024 bf16 (hi only) = 2097152 float-slots
#define WS_BPACK    5014528   // 1024*512 bf16 (hi only) = 262144 float-slots

__device__ __forceinline__ float gelu_f(float x) {
    return 0.5f * x * (1.0f + erff(x * 0.70710678118654752f));
}
__device__ __forceinline__ float sigm_f(float x) {
    return 1.0f / (1.0f + expf(-x));
}
__device__ __forceinline__ short f2bf(float f) {   // RNE float->bf16
    unsigned u = __float_as_uint(f);
    u += 0x7fffu + ((u >> 16) & 1u);
    return (short)(u >> 16);
}

// row r in [0,4096) = p*2048 + pos*64 + b  ->  source seq index s
__device__ __forceinline__ int row_to_s(int r) {
    int p = r >> 11, pos = (r & 2047) >> 6;
    return p ? pos * 128 : 4064 + pos;
}

// ---------------- K1: prep (ctx partials | A-pack | B-pack | attn fill) ----------------
__global__ __launch_bounds__(256) void prep_k(const float* __restrict__ long_x,
                                              const float* __restrict__ enc,
                                              const float* __restrict__ rs_w1,
                                              float* __restrict__ pbuf,
                                              short* __restrict__ Apack,
                                              short* __restrict__ Bpack,
                                              float* __restrict__ attn_out) {
    int blk = blockIdx.x, t = threadIdx.x;
    if (blk < 512) {
        // encoded_x (512,64,1024) -> partial[8][64][1024]
        int gt = blk * 256 + t;
        int chunk = gt >> 14, idx = gt & 16383;   // idx = b*256 + e4
        const float4* src = reinterpret_cast<const float4*>(enc) + idx;
        float sx = 0.f, sy = 0.f, sz = 0.f, sw = 0.f;
        int s0 = chunk * 64;
        for (int s = s0; s < s0 + 64; ++s) {
            float4 v = src[(size_t)s * 16384];
            sx += v.x; sy += v.y; sz += v.z; sw += v.w;
        }
        float4 o; o.x = sx; o.y = sy; o.z = sz; o.w = sw;
        reinterpret_cast<float4*>(pbuf)[(size_t)chunk * 16384 + idx] = o;
    } else if (blk < 1024) {
        // A-pack (hi only), coalesced reads: thread = (row r, kt). 128B contiguous read.
        int ti = (blk - 512) * 256 + t;         // [0, 131072)
        int r  = ti >> 5, kt = ti & 31;
        int b  = r & 63;
        int s  = row_to_s(r);
        const float4* src = reinterpret_cast<const float4*>(
            long_x + ((size_t)s * 64 + b) * 1024 + kt * 32);
        float fs[32];
        #pragma unroll
        for (int q = 0; q < 8; ++q) {
            float4 v = src[q];
            fs[q * 4 + 0] = v.x; fs[q * 4 + 1] = v.y;
            fs[q * 4 + 2] = v.z; fs[q * 4 + 3] = v.w;
        }
        int mt = r >> 4, lo16 = r & 15;
        bf16x8* dst = reinterpret_cast<bf16x8*>(Apack);
        #pragma unroll
        for (int hi4 = 0; hi4 < 4; ++hi4) {
            bf16x8 h;
            #pragma unroll
            for (int j = 0; j < 8; ++j) h[j] = f2bf(fs[hi4 * 8 + j]);
            dst[(size_t)(mt * 32 + kt) * 64 + hi4 * 16 + lo16] = h;
        }
    } else if (blk < 1280) {
        // B-pack (hi only): fragment (nt,kt,lane): rs_w1[kt*32+(l>>4)*8 + j][nt*16+(l&15)]
        int ti = (blk - 1024) * 256 + t;        // [0, 65536)
        int lane = ti & 63, kt = (ti >> 6) & 31, nt = ti >> 11;
        int k0 = kt * 32 + (lane >> 4) * 8;
        int col = nt * 16 + (lane & 15);
        bf16x8 h;
        #pragma unroll
        for (int j = 0; j < 8; ++j) h[j] = f2bf(rs_w1[(size_t)(k0 + j) * 512 + col]);
        reinterpret_cast<bf16x8*>(Bpack)[ti] = h;
    } else {
        // attn = 1/4096 : 65536 float4
        int i = (blk - 1280) * 256 + t;
        float4 v; v.x = v.y = v.z = v.w = (1.0f / 4096.0f);
        reinterpret_cast<float4*>(attn_out)[i] = v;
    }
}

// ---------------- K2: heads v4 — 512 thr (8 K-strips), 2 waves/SIMD ----------------
// 256 blocks: role = blk>>7, bq = (blk>>3)&15, jc = blk&7. thr = (jl 64) x (kh 8).
__global__ __launch_bounds__(512) void heads_k(const float* __restrict__ pbuf,
                                               const float* __restrict__ rs_w1,
                                               const float* __restrict__ rs_b1,
                                               const float* __restrict__ sp_w1,
                                               const float* __restrict__ sp_b1,
                                               const float* __restrict__ sp_w2,
                                               const float* __restrict__ sp_b2,
                                               float* __restrict__ ctxproj,
                                               float* __restrict__ spanpart) {
    __shared__ float c4[4][1024];
    __shared__ float sums[8][64][4];
    __shared__ float r0[4][64], r1[4][64];
    int blk = blockIdx.x, t = threadIdx.x;
    int role = blk >> 7;
    int bq = (blk >> 3) & 15, jc = blk & 7;
    int b0 = bq * 4, j0 = jc * 64;
    // stage ctx rows b0..b0+3 (mean over enc partials)
    for (int e = t; e < 4096; e += 512) {
        int b = e >> 10, k = e & 1023;
        float s = 0.f;
        #pragma unroll
        for (int cc = 0; cc < 8; ++cc) s += pbuf[((size_t)(cc * 64 + b0 + b)) * 1024 + k];
        c4[b][k] = s * (1.0f / 512.0f);
    }
    __syncthreads();
    int jl = t & 63, kh = t >> 6;     // kh 0..7, strips of 128 k
    int j = j0 + jl;
    const float* w = (role == 0 ? rs_w1 + (size_t)1024 * 512 : sp_w1)
                     + (size_t)(kh * 128) * 512 + j;
    float acc[4] = {0.f, 0.f, 0.f, 0.f};
    #pragma unroll 8
    for (int k = 0; k < 128; ++k) {
        float wv = w[(size_t)k * 512];
        int kk = kh * 128 + k;
        acc[0] += c4[0][kk] * wv;
        acc[1] += c4[1][kk] * wv;
        acc[2] += c4[2][kk] * wv;
        acc[3] += c4[3][kk] * wv;
    }
    #pragma unroll
    for (int b = 0; b < 4; ++b) sums[kh][jl][b] = acc[b];
    __syncthreads();
    // threads 0..255: (jl2 = t>>2, b = t&3): combine 8 kh partials
    if (t < 256) {
        int jl2 = t >> 2, b = t & 3;
        float val = 0.f;
        #pragma unroll
        for (int q = 0; q < 8; ++q) val += sums[q][jl2][b];
        int jj = j0 + jl2, gb = b0 + b;
        if (role == 0) {
            ctxproj[(size_t)gb * 512 + jj] = rs_b1[jj] + val;
        } else {
            float h = gelu_f(sp_b1[jj] + val);
            r0[b][jl2] = h * sp_w2[jj * 2 + 0];
            r1[b][jl2] = h * sp_w2[jj * 2 + 1];
        }
    }
    if (role == 1) {
        __syncthreads();
        for (int s = 32; s > 0; s >>= 1) {
            if (t < 4 * s) {
                int bb = t / s, qq = t % s;
                r0[bb][qq] += r0[bb][qq + s];
                r1[bb][qq] += r1[bb][qq + s];
            }
            __syncthreads();
        }
        if (t < 4) {
            spanpart[((size_t)(b0 + t) * 8 + jc) * 2 + 0] = r0[t][0];
            spanpart[((size_t)(b0 + t) * 8 + jc) * 2 + 1] = r1[t][0];
        }
    }
}

// ---------------- K3: score GEMM via MFMA, pure bf16-hi, 8 waves (2 waves/SIMD) -------
__global__ __launch_bounds__(512) void score_mfma_k(const short* __restrict__ Apack_,
                                                    const short* __restrict__ Bpack_,
                                                    const float* __restrict__ ctxproj,
                                                    const float* __restrict__ rs_w2,
                                                    float* __restrict__ part) {
    const bf16x8* Apack = reinterpret_cast<const bf16x8*>(Apack_);
    const bf16x8* Bpack = reinterpret_cast<const bf16x8*>(Bpack_);
    int t = threadIdx.x, lane = t & 63, w = t >> 6;
    int wr = w & 1, wc = w >> 1;                      // 2 x 4 wave grid
    int bm = blockIdx.x & 63, bn = blockIdx.x >> 6;   // XCD-local A-reuse swizzle
    int mt0 = bm * 4 + wr * 2;      // 2 m-fragments
    int nt0 = bn * 8 + wc * 2;      // 2 n-fragments
    f32x4 acc[2][2];
    #pragma unroll
    for (int r = 0; r < 2; ++r)
        #pragma unroll
        for (int i = 0; i < 2; ++i) acc[r][i] = (f32x4){0.f, 0.f, 0.f, 0.f};
    const bf16x8* A0 = Apack + ((size_t)(mt0 + 0) * 2048 + lane);
    const bf16x8* A1 = Apack + ((size_t)(mt0 + 1) * 2048 + lane);
    const bf16x8* B0 = Bpack + ((size_t)(nt0 + 0) * 2048 + lane);
    const bf16x8* B1 = Bpack + ((size_t)(nt0 + 1) * 2048 + lane);
    #pragma unroll 4
    for (int kt = 0; kt < 32; ++kt) {
        bf16x8 a0 = A0[kt * 64];
        bf16x8 a1 = A1[kt * 64];
        bf16x8 b0 = B0[kt * 64];
        bf16x8 b1 = B1[kt * 64];
        acc[0][0] = __builtin_amdgcn_mfma_f32_16x16x32_bf16(a0, b0, acc[0][0], 0, 0, 0);
        acc[0][1] = __builtin_amdgcn_mfma_f32_16x16x32_bf16(a0, b1, acc[0][1], 0, 0, 0);
        acc[1][0] = __builtin_amdgcn_mfma_f32_16x16x32_bf16(a1, b0, acc[1][0], 0, 0, 0);
        acc[1][1] = __builtin_amdgcn_mfma_f32_16x16x32_bf16(a1, b1, acc[1][1], 0, 0, 0);
    }
    // epilogue: + ctxproj, gelu, dot rs_w2 over this wave's 32 cols, 16-lane reduce
    int hi = lane >> 4, lo = lane & 15;
    int c0 = (nt0 + 0) * 16 + lo, c1 = (nt0 + 1) * 16 + lo;
    float w2c0 = rs_w2[c0], w2c1 = rs_w2[c1];
    float pl[8];
    #pragma unroll
    for (int rr = 0; rr < 2; ++rr) {
        #pragma unroll
        for (int reg = 0; reg < 4; ++reg) {
            int row = (mt0 + rr) * 16 + hi * 4 + reg;
            int b = row & 63;
            pl[rr * 4 + reg] =
                gelu_f(acc[rr][0][reg] + ctxproj[(size_t)b * 512 + c0]) * w2c0 +
                gelu_f(acc[rr][1][reg] + ctxproj[(size_t)b * 512 + c1]) * w2c1;
        }
    }
    #pragma unroll
    for (int m = 1; m < 16; m <<= 1) {
        #pragma unroll
        for (int q = 0; q < 8; ++q) pl[q] += __shfl_xor(pl[q], m, 64);
    }
    if (lo == 0) {
        int chunk = bn * 4 + wc;   // [0,16)
        #pragma unroll
        for (int rr = 0; rr < 2; ++rr)
            #pragma unroll
            for (int reg = 0; reg < 4; ++reg) {
                int row = (mt0 + rr) * 16 + hi * 4 + reg;
                part[(size_t)row * 16 + chunk] = pl[rr * 4 + reg];
            }
    }
}

// ---------------- K4: pool v2 — 512 thr, l-range split 2x16, LDS combine --------------
__global__ __launch_bounds__(512) void pool_k(const float* __restrict__ long_x,
                                              const float* __restrict__ part,
                                              const float* __restrict__ rs_b2,
                                              const float* __restrict__ decay_l,
                                              const float* __restrict__ decay_g,
                                              float* __restrict__ feats) {
    __shared__ float red[32][16];
    __shared__ float wl[32];
    __shared__ float4 tmp[256];
    int blk = blockIdx.x;
    int p = blk >> 6, b = blk & 63;
    int t = threadIdx.x;
    if (t < 512) {
        int pos = t >> 4, cc = t & 15;
        red[pos][cc] = part[(size_t)(p * 2048 + pos * 64 + b) * 16 + cc];
    }
    __syncthreads();
    if (t < 32) {
        float z = rs_b2[0];
        #pragma unroll
        for (int q = 0; q < 16; ++q) z += red[t][q];
        float sc = sigm_f(z);
        float decay = p ? decay_g[0] : decay_l[0];
        float dec = powf(decay, (float)(31 - t));
        wl[t] = sc + logf(dec + 1e-8f);
    }
    __syncthreads();
    if (t == 0) {
        float m = -1e30f;
        for (int j = 0; j < 32; ++j) m = fmaxf(m, wl[j]);
        float ssum = 0.f;
        float e[32];
        for (int j = 0; j < 32; ++j) { e[j] = expf(wl[j] - m); ssum += e[j]; }
        float inv = 1.0f / ssum;
        for (int j = 0; j < 32; ++j) wl[j] = e[j] * inv;
    }
    __syncthreads();
    int e4 = t & 255, lh = t >> 8;    // lh 0..1: 16 l each
    float sx = 0.f, sy = 0.f, sz = 0.f, sw = 0.f;
    #pragma unroll 8
    for (int li = 0; li < 16; ++li) {
        int l = lh * 16 + li;
        int s = p ? (l * 128) : (4064 + l);
        float4 v = reinterpret_cast<const float4*>(long_x)[((size_t)s * 64 + b) * 256 + e4];
        float wv = wl[l];
        sx += wv * v.x; sy += wv * v.y; sz += wv * v.z; sw += wv * v.w;
    }
    if (lh == 1) {
        float4 u; u.x = sx; u.y = sy; u.z = sz; u.w = sw;
        tmp[e4] = u;
    }
    __syncthreads();
    if (lh == 0) {
        float4 u = tmp[e4];
        float4 o; o.x = sx + u.x; o.y = sy + u.y; o.z = sz + u.z; o.w = sw + u.w;
        reinterpret_cast<float4*>(feats)[((size_t)(p * 64 + b)) * 256 + e4] = o;
    }
}

// ---------------- K5: fused partial GEMM (combined @ fu_w), 16-way split-K ------------
__global__ __launch_bounds__(256) void fu_partial_k(const float* __restrict__ feats,
                                                    const float* __restrict__ spanpart,
                                                    const float* __restrict__ sp_b2,
                                                    const float* __restrict__ fu_w,
                                                    float* __restrict__ pbufA) {
    __shared__ float a[64][132];
    __shared__ float sw[64][2];
    int kchunk = blockIdx.x >> 4;   // 0..15 (128 k each)
    int nt     = blockIdx.x & 15;   // 0..15 (64 cols each)
    int t = threadIdx.x;
    if (t < 64) {
        float s0 = 0.f, s1 = 0.f;
        #pragma unroll
        for (int q = 0; q < 8; ++q) {
            s0 += spanpart[((size_t)t * 8 + q) * 2 + 0];
            s1 += spanpart[((size_t)t * 8 + q) * 2 + 1];
        }
        float l0 = s0 + sp_b2[0], l1 = s1 + sp_b2[1];
        float m = fmaxf(l0, l1);
        float e0 = expf(l0 - m), e1 = expf(l1 - m), inv = 1.0f / (e0 + e1);
        sw[t][0] = e0 * inv; sw[t][1] = e1 * inv;
    }
    __syncthreads();
    int p = kchunk >> 3, kbase = (kchunk & 7) * 128;
    int colq = t & 15, bg = t >> 4;
    #pragma unroll
    for (int it = 0; it < 8; ++it) {
        int idx = t + it * 256;            // 2048 float4 = 64 b x 32 kq
        int b = idx >> 5, kq = idx & 31;
        float4 v = *reinterpret_cast<const float4*>(
            feats + ((size_t)(p * 64 + b)) * 1024 + kbase + kq * 4);
        float sc = sw[b][p];
        v.x *= sc; v.y *= sc; v.z *= sc; v.w *= sc;
        *reinterpret_cast<float4*>(&a[b][kq * 4]) = v;
    }
    __syncthreads();
    float acc[4][4] = {};
    #pragma unroll 4
    for (int k = 0; k < 128; ++k) {
        float4 wv = *reinterpret_cast<const float4*>(
            fu_w + (size_t)(kchunk * 128 + k) * 1024 + nt * 64 + colq * 4);
        #pragma unroll
        for (int i = 0; i < 4; ++i) {
            float av = a[bg * 4 + i][k];
            acc[i][0] += av * wv.x; acc[i][1] += av * wv.y;
            acc[i][2] += av * wv.z; acc[i][3] += av * wv.w;
        }
    }
    #pragma unroll
    for (int i = 0; i < 4; ++i) {
        float4 o; o.x = acc[i][0]; o.y = acc[i][1]; o.z = acc[i][2]; o.w = acc[i][3];
        *reinterpret_cast<float4*>(
            pbufA + ((size_t)(kchunk * 64 + bg * 4 + i)) * 1024 + nt * 64 + colq * 4) = o;
    }
}

// ---------------- K5b: fused = gelu(sum fu-partials + fu_b), computed ONCE ------------
__global__ __launch_bounds__(256) void fu_final_k(const float* __restrict__ pbufA,
                                                  const float* __restrict__ fu_b,
                                                  float* __restrict__ fused) {
    int i4 = blockIdx.x * 256 + threadIdx.x;   // 16384 float4
    int bi = (i4 * 4) & 1023;
    float4 z; z.x = fu_b[bi]; z.y = fu_b[bi + 1]; z.z = fu_b[bi + 2]; z.w = fu_b[bi + 3];
    #pragma unroll
    for (int c = 0; c < 16; ++c) {
        float4 v = reinterpret_cast<const float4*>(pbufA)[(size_t)c * 16384 + i4];
        z.x += v.x; z.y += v.y; z.z += v.z; z.w += v.w;
    }
    float4 o;
    o.x = gelu_f(z.x); o.y = gelu_f(z.y); o.z = gelu_f(z.z); o.w = gelu_f(z.w);
    reinterpret_cast<float4*>(fused)[i4] = o;
}

// ---------------- K6: gate partial GEMM (fused @ g_w), 16-way split-K -----------------
__global__ __launch_bounds__(256) void g_partial_k(const float* __restrict__ fused,
                                                   const float* __restrict__ g_w,
                                                   float* __restrict__ pbufB) {
    __shared__ float a[64][68];
    int kchunk = blockIdx.x >> 4;   // 0..15 (64 k each)
    int nt     = blockIdx.x & 15;
    int t = threadIdx.x;
    int k0 = kchunk * 64;
    #pragma unroll
    for (int it = 0; it < 4; ++it) {
        int idx = t + it * 256;            // 1024 float4 = 64 b x 16 kq
        int b = idx >> 4, kq = idx & 15;
        float4 z = *reinterpret_cast<const float4*>(fused + (size_t)b * 1024 + k0 + kq * 4);
        *reinterpret_cast<float4*>(&a[b][kq * 4]) = z;
    }
    __syncthreads();
    int colq = t & 15, bg = t >> 4;
    float acc[4][4] = {};
    #pragma unroll 4
    for (int k = 0; k < 64; ++k) {
        float4 wv = *reinterpret_cast<const float4*>(
            g_w + (size_t)(k0 + k) * 1024 + nt * 64 + colq * 4);
        #pragma unroll
        for (int i = 0; i < 4; ++i) {
            float av = a[bg * 4 + i][k];
            acc[i][0] += av * wv.x; acc[i][1] += av * wv.y;
            acc[i][2] += av * wv.z; acc[i][3] += av * wv.w;
        }
    }
    #pragma unroll
    for (int i = 0; i < 4; ++i) {
        float4 o; o.x = acc[i][0]; o.y = acc[i][1]; o.z = acc[i][2]; o.w = acc[i][3];
        *reinterpret_cast<float4*>(
            pbufB + ((size_t)(kchunk * 64 + bg * 4 + i)) * 1024 + nt * 64 + colq * 4) = o;
    }
}

// ---------------- K7: adaptive = fused * sigmoid(sum gate partials + g_b) -------------
__global__ __launch_bounds__(256) void g_final_k(const float* __restrict__ pbufB,
                                                 const float* __restrict__ g_b,
                                                 const float* __restrict__ fused,
                                                 float* __restrict__ out_adaptive) {
    int i4 = blockIdx.x * 256 + threadIdx.x;   // 16384 float4
    int bi = (i4 * 4) & 1023;
    float4 z; z.x = g_b[bi]; z.y = g_b[bi + 1]; z.z = g_b[bi + 2]; z.w = g_b[bi + 3];
    #pragma unroll
    for (int c = 0; c < 16; ++c) {
        float4 v = reinterpret_cast<const float4*>(pbufB)[(size_t)c * 16384 + i4];
        z.x += v.x; z.y += v.y; z.z += v.z; z.w += v.w;
    }
    float4 f = reinterpret_cast<const float4*>(fused)[i4];
    float4 o;
    o.x = f.x * sigm_f(z.x); o.y = f.y * sigm_f(z.y);
    o.z = f.z * sigm_f(z.z); o.w = f.w * sigm_f(z.w);
    reinterpret_cast<float4*>(out_adaptive)[i4] = o;
}

// ---------------- launch ----------------
extern "C" void kernel_launch(void* const* d_in, const int* in_sizes, int n_in,
                              void* d_out, int out_size, void* d_ws, size_t ws_size,
                              hipStream_t stream) {
    const float* long_x  = (const float*)d_in[0];
    const float* enc     = (const float*)d_in[1];
    const float* sp_w1   = (const float*)d_in[2];
    const float* sp_b1   = (const float*)d_in[3];
    const float* sp_w2   = (const float*)d_in[4];
    const float* sp_b2   = (const float*)d_in[5];
    const float* rs_w1   = (const float*)d_in[6];
    const float* rs_b1   = (const float*)d_in[7];
    const float* rs_w2   = (const float*)d_in[8];
    const float* rs_b2   = (const float*)d_in[9];
    const float* fu_w    = (const float*)d_in[10];
    const float* fu_b    = (const float*)d_in[11];
    const float* g_w     = (const float*)d_in[12];
    const float* g_b     = (const float*)d_in[13];
    const float* decay_l = (const float*)d_in[14];
    const float* decay_g = (const float*)d_in[15];

    float* out = (float*)d_out;
    float* ws  = (float*)d_ws;

    prep_k<<<1536, 256, 0, stream>>>(long_x, enc, rs_w1, ws + WS_PBUF,
                                     (short*)(ws + WS_APACK), (short*)(ws + WS_BPACK), out);
    heads_k<<<256, 512, 0, stream>>>(ws + WS_PBUF, rs_w1, rs_b1, sp_w1, sp_b1, sp_w2, sp_b2,
                                     ws + WS_CTXPROJ, ws + WS_SPANPART);
    score_mfma_k<<<256, 512, 0, stream>>>((short*)(ws + WS_APACK), (short*)(ws + WS_BPACK),
                                          ws + WS_CTXPROJ, rs_w2, ws + WS_PART);
    pool_k<<<128, 512, 0, stream>>>(long_x, ws + WS_PART, rs_b2, decay_l, decay_g,
                                    ws + WS_FEATS);
    fu_partial_k<<<256, 256, 0, stream>>>(ws + WS_FEATS, ws + WS_SPANPART, sp_b2, fu_w,
                                          ws + WS_PBUFA);
    fu_final_k<<<64, 256, 0, stream>>>(ws + WS_PBUFA, fu_b, ws + WS_FUSED);
    g_partial_k<<<256, 256, 0, stream>>>(ws + WS_FUSED, g_w, ws + WS_PBUFB);
    g_final_k<<<64, 256, 0, stream>>>(ws + WS_PBUFB, g_b, ws + WS_FUSED, out + 262144);
}